// Round 7
// baseline (230.952 us; speedup 1.0000x reference)
//
#include <hip/hip_runtime.h>

// LIF neuron scan: x[T,B,D] f32, v0[D] f32 -> spikes[T,B,D] f32.
// T=512, B=64, D=1024. tau=0.5 (exact mul), threshold=1.0, v_reset=0.0.
//
// R1: naive 1-thread/chain -> 80-85us, 2.5 TB/s, VGPR=28 (W~2 in flight).
// R4: ping-pong U=16 prefetch        -> ~77us (inferred from bench dur).
// R6: triple-buffer + sched_barrier  -> ~77us. ILP restructuring is inert:
//     effective W stays ~3-4/wave regardless of source schedule.
// R7: raise TLP instead. Speculative T-chunking: 4 chunks x 128 steps;
//     chunks 1-3 redo a 64-step warm-up from v=0 (reads only). tau=0.5
//     contracts state error x0.5/step and any shared reset snaps v to an
//     exact 0.0 -> bit-exact convergence whp well before 64 steps.
//     4096 waves (4/SIMD): in-flight = waves x W x 256B no longer depends
//     on per-wave compiler scheduling. Extra reads: 48 MB (L3-friendly).

constexpr int T_STEPS  = 512;
constexpr int B_DIM    = 64;
constexpr int D_DIM    = 1024;
constexpr int N_CHAIN  = B_DIM * D_DIM;      // 65536 chains
constexpr int C_CHUNKS = 4;
constexpr int T_CHUNK  = T_STEPS / C_CHUNKS; // 128
constexpr int K_WARM   = 64;                 // warm-up steps (no stores)
constexpr int U        = 8;                  // ping-pong prefetch depth

// Ping-pong prefetched serial LIF scan over [tbase, tbase+STEPS).
// STORE=false: warm-up (state only). All buffer indexing is compile-time.
template<bool STORE, int STEPS>
__device__ __forceinline__ void scan_range(const float* __restrict__ xp,
                                           float* __restrict__ op,
                                           int tbase, float& v) {
    float bufA[U], bufB[U];
#pragma unroll
    for (int u = 0; u < U; ++u)
        bufA[u] = xp[(size_t)(tbase + u) * N_CHAIN];

    for (int t0 = 0; t0 < STEPS; t0 += 2 * U) {
#pragma unroll
        for (int u = 0; u < U; ++u)
            bufB[u] = xp[(size_t)(tbase + t0 + U + u) * N_CHAIN];
#pragma unroll
        for (int u = 0; u < U; ++u) {
            v = v * 0.5f + bufA[u];           // exact: tau = 0.5
            const bool s = (v >= 1.0f);
            if (STORE)
                __builtin_nontemporal_store(s ? 1.0f : 0.0f,
                    op + (size_t)(tbase + t0 + u) * N_CHAIN);
            v = s ? 0.0f : v;
        }
        const int tn = t0 + 2 * U;
        if (tn < STEPS) {
#pragma unroll
            for (int u = 0; u < U; ++u)
                bufA[u] = xp[(size_t)(tbase + tn + u) * N_CHAIN];
        }
#pragma unroll
        for (int u = 0; u < U; ++u) {
            v = v * 0.5f + bufB[u];
            const bool s = (v >= 1.0f);
            if (STORE)
                __builtin_nontemporal_store(s ? 1.0f : 0.0f,
                    op + (size_t)(tbase + t0 + U + u) * N_CHAIN);
            v = s ? 0.0f : v;
        }
    }
}

__global__ __launch_bounds__(256)
void lif_scan_kernel(const float* __restrict__ x,
                     const float* __restrict__ v0,
                     float* __restrict__ out) {
    // 1024 blocks: low 8 bits pick the chain slab, high bits pick the chunk.
    const int chain = ((blockIdx.x & 255) << 8) + threadIdx.x;  // 0..65535
    const int chunk = blockIdx.x >> 8;                          // 0..3
    const int d     = chain & (D_DIM - 1);

    const float* xp = x   + chain;
    float*       op = out + chain;

    float v;
    if (chunk == 0) {
        v = v0[d];                                   // exact start
        scan_range<true, T_CHUNK>(xp, op, 0, v);
    } else {
        v = 0.0f;                                    // speculative start
        const int t0 = chunk * T_CHUNK;
        scan_range<false, K_WARM>(xp, op, t0 - K_WARM, v);   // converge v
        scan_range<true,  T_CHUNK>(xp, op, t0, v);           // emit spikes
    }
}

extern "C" void kernel_launch(void* const* d_in, const int* in_sizes, int n_in,
                              void* d_out, int out_size, void* d_ws, size_t ws_size,
                              hipStream_t stream) {
    const float* x   = (const float*)d_in[0];
    const float* v0  = (const float*)d_in[1];
    float*       out = (float*)d_out;

    dim3 block(256);
    dim3 grid(C_CHUNKS * (N_CHAIN / 256));   // 1024 blocks -> 4 waves/SIMD
    hipLaunchKernelGGL(lif_scan_kernel, grid, block, 0, stream, x, v0, out);
}